// Round 1
// baseline (4480.575 us; speedup 1.0000x reference)
//
#include <hip/hip_runtime.h>
#include <cstdint>
#include <cstddef>

#define NFEATS 128
#define NHIDS  128
#define NOUT   64

// ---------------------------------------------------------------------------
// Edge-index dtype detection: read first 64 entries as int64. If the buffer is
// really int32 pairs, reinterpreted values are >= 2^32 (unless the high word
// happens to be 0, p~2e-5 per element -> any-of-64 is certain in practice).
// flag = 1  -> buffer is int32
// flag = 0  -> buffer is int64
// ---------------------------------------------------------------------------
__global__ void detect_kernel(const void* p, int* flag, long long n_nodes) {
    const long long* q = (const long long*)p;
    long long v = q[threadIdx.x];          // 64 threads = 1 wave
    int bad = (v < 0 || v >= n_nodes) ? 1 : 0;
    unsigned long long m = __ballot(bad);
    if (threadIdx.x == 0) *flag = (m != 0ULL) ? 1 : 0;
}

__global__ void convert_kernel(const void* p, int* out, int n, const int* flag) {
    int i = blockIdx.x * blockDim.x + threadIdx.x;
    if (i < n) {
        if (*flag) out[i] = ((const int*)p)[i];
        else       out[i] = (int)((const long long*)p)[i];
    }
}

// ---------------------------------------------------------------------------
// Degree of (A + I) restricted to dst, then dinv = rsqrt(deg+1)
// ---------------------------------------------------------------------------
__global__ void deg_init(int* deg, int n) {
    int i = blockIdx.x * blockDim.x + threadIdx.x;
    if (i < n) deg[i] = 0;
}

__global__ void deg_count(const int* __restrict__ dst, int* __restrict__ deg, int ne) {
    int i = blockIdx.x * blockDim.x + threadIdx.x;
    if (i < ne) atomicAdd(&deg[dst[i]], 1);
}

__global__ void dinv_kernel(const int* __restrict__ deg, float* __restrict__ dinv, int n) {
    int i = blockIdx.x * blockDim.x + threadIdx.x;
    if (i < n) dinv[i] = rsqrtf((float)(deg[i] + 1));
}

// ---------------------------------------------------------------------------
// hs[r][c] = dinv[r] * sum_k X[r][k] * W[k][c]; also writes acc = hs
// (acc starts at the self-loop term). K = 128 fixed. NC in {128, 64}.
// Block = 256 threads, each thread computes 16 contiguous output cols of one
// row. RPB = 256 / (NC/16) rows per block.
// ---------------------------------------------------------------------------
template <int NC, int RPB>
__launch_bounds__(256)
__global__ void gemm_scale(const float* __restrict__ X, const float* __restrict__ W,
                           const float* __restrict__ dinv,
                           float* __restrict__ hs, float* __restrict__ acc, int nrows) {
    constexpr int K   = 128;
    constexpr int TPR = NC / 16;                 // threads per row
    constexpr int XLD = K + 4;                   // padded X stride (bank spread)
    __shared__ float Wl[K * NC];
    __shared__ float Xl[RPB * XLD];

    const int tid  = threadIdx.x;
    const int row0 = blockIdx.x * RPB;

    // stage W (K*NC floats)
    for (int i = tid; i < K * NC / 4; i += 256)
        ((float4*)Wl)[i] = ((const float4*)W)[i];

    // stage X rows (RPB * K floats)
    for (int i = tid; i < RPB * K / 4; i += 256) {
        int r = i / (K / 4);
        int c = i % (K / 4);
        int gr = row0 + r;
        float4 v = (gr < nrows) ? ((const float4*)(X + (size_t)gr * K))[c]
                                : make_float4(0.f, 0.f, 0.f, 0.f);
        *((float4*)(Xl + r * XLD + c * 4)) = v;
    }
    __syncthreads();

    const int rl = tid / TPR;
    const int c0 = (tid % TPR) * 16;
    float a[16];
#pragma unroll
    for (int j = 0; j < 16; ++j) a[j] = 0.f;

    const float* xp = Xl + rl * XLD;
#pragma unroll 4
    for (int k = 0; k < K; ++k) {
        float xv = xp[k];
#pragma unroll
        for (int j = 0; j < 16; ++j)
            a[j] += xv * Wl[k * NC + c0 + j];
    }

    int gr = row0 + rl;
    if (gr < nrows) {
        float dv = dinv[gr];
        float* hp = hs  + (size_t)gr * NC + c0;
        float* ap = acc + (size_t)gr * NC + c0;
#pragma unroll
        for (int j = 0; j < 16; ++j) {
            float v = a[j] * dv;
            hp[j] = v;
            ap[j] = v;
        }
    }
}

// ---------------------------------------------------------------------------
// Edge aggregation: acc[dst] += hs[src]   (F/4 threads per edge, float4 each)
// ---------------------------------------------------------------------------
template <int F>
__global__ void aggregate(const int* __restrict__ src, const int* __restrict__ dst,
                          const float* __restrict__ hs, float* __restrict__ acc, int ne) {
    constexpr int TPE = F / 4;
    long long tid = (long long)blockIdx.x * blockDim.x + threadIdx.x;
    int e = (int)(tid / TPE);
    if (e < ne) {
        int c = ((int)tid % TPE) * 4;
        int s = src[e];
        int d = dst[e];
        float4 v = *(const float4*)(hs + (size_t)s * F + c);
        float* a = acc + (size_t)d * F + c;
        unsafeAtomicAdd(a + 0, v.x);
        unsafeAtomicAdd(a + 1, v.y);
        unsafeAtomicAdd(a + 2, v.z);
        unsafeAtomicAdd(a + 3, v.w);
    }
}

// ---------------------------------------------------------------------------
// out[r][c] = (relu?)(acc[r][c] * dinv[r] + b[c])
// ---------------------------------------------------------------------------
template <int F, bool RELU>
__global__ void epilogue(const float* __restrict__ acc, const float* __restrict__ dinv,
                         const float* __restrict__ b, float* __restrict__ out, int n) {
    long long tid = (long long)blockIdx.x * blockDim.x + threadIdx.x;
    if (tid < (long long)n * F) {
        int r = (int)(tid / F);
        int c = (int)(tid % F);
        float v = acc[tid] * dinv[r] + b[c];
        if (RELU) v = fmaxf(v, 0.f);
        out[tid] = v;
    }
}

// ---------------------------------------------------------------------------
extern "C" void kernel_launch(void* const* d_in, const int* in_sizes, int n_in,
                              void* d_out, int out_size, void* d_ws, size_t ws_size,
                              hipStream_t stream) {
    const void*  edge = d_in[0];
    const float* x    = (const float*)d_in[1];
    const float* W1   = (const float*)d_in[2];
    const float* b1   = (const float*)d_in[3];
    const float* W2   = (const float*)d_in[4];
    const float* b2   = (const float*)d_in[5];
    float* out = (float*)d_out;

    const int E = in_sizes[0] / 2;          // edge_index is [2, E]
    const int N = in_sizes[1] / NFEATS;     // 100000

    // ---- workspace carve (all offsets 16B-aligned) ----
    char* w = (char*)d_ws;
    int*   flag  = (int*)w;                 w += 256;
    int*   src32 = (int*)w;                 w += sizeof(int) * (size_t)E;
    int*   dst32 = (int*)w;                 w += sizeof(int) * (size_t)E;
    int*   deg   = (int*)w;                 w += sizeof(int) * (size_t)N;
    float* dinv  = (float*)w;               w += sizeof(float) * (size_t)N;
    float* hs1   = (float*)w;               w += sizeof(float) * (size_t)N * NHIDS;
    float* acc1  = (float*)w;               w += sizeof(float) * (size_t)N * NHIDS;
    float* hs2   = (float*)w;               w += sizeof(float) * (size_t)N * NOUT;
    float* acc2  = (float*)w;               w += sizeof(float) * (size_t)N * NOUT;

    const int B = 256;

    // edge-index normalization
    detect_kernel<<<1, 64, 0, stream>>>(edge, flag, (long long)N);
    convert_kernel<<<(2 * E + B - 1) / B, B, 0, stream>>>(edge, src32, 2 * E, flag);

    // degrees -> dinv
    deg_init<<<(N + B - 1) / B, B, 0, stream>>>(deg, N);
    deg_count<<<(E + B - 1) / B, B, 0, stream>>>(dst32, deg, E);
    dinv_kernel<<<(N + B - 1) / B, B, 0, stream>>>(deg, dinv, N);

    // ---- layer 1: hs1 = (x @ W1) * dinv ; acc1 = hs1 (self loop) ----
    gemm_scale<NHIDS, 32><<<(N + 31) / 32, B, 0, stream>>>(x, W1, dinv, hs1, acc1, N);
    {
        long long work = (long long)E * (NHIDS / 4);
        aggregate<NHIDS><<<(int)((work + B - 1) / B), B, 0, stream>>>(src32, dst32, hs1, acc1, E);
    }
    // h = relu(acc1 * dinv + b1), written back into hs1's buffer
    {
        long long work = (long long)N * NHIDS;
        epilogue<NHIDS, true><<<(int)((work + B - 1) / B), B, 0, stream>>>(acc1, dinv, b1, hs1, N);
    }

    // ---- layer 2: hs2 = (h @ W2) * dinv ; acc2 = hs2 ----
    gemm_scale<NOUT, 64><<<(N + 63) / 64, B, 0, stream>>>(hs1, W2, dinv, hs2, acc2, N);
    {
        long long work = (long long)E * (NOUT / 4);
        aggregate<NOUT><<<(int)((work + B - 1) / B), B, 0, stream>>>(src32, dst32, hs2, acc2, E);
    }
    {
        long long work = (long long)N * NOUT;
        epilogue<NOUT, false><<<(int)((work + B - 1) / B), B, 0, stream>>>(acc2, dinv, b2, out, N);
    }
}

// Round 3
// 801.200 us; speedup vs baseline: 5.5923x; 5.5923x over previous
//
#include <hip/hip_runtime.h>
#include <cstdint>
#include <cstddef>

#define NFEATS 128
#define NHIDS  128
#define NOUT   64

// ---------------------------------------------------------------------------
// Edge-index dtype detection: read first 64 entries as int64. If the buffer is
// really int32 pairs, reinterpreted values are >= n_nodes almost surely.
// flag = 1 -> int32, flag = 0 -> int64
// ---------------------------------------------------------------------------
__global__ void detect_kernel(const void* p, int* flag, long long n_nodes) {
    const long long* q = (const long long*)p;
    long long v = q[threadIdx.x];          // 64 threads = 1 wave
    int bad = (v < 0 || v >= n_nodes) ? 1 : 0;
    unsigned long long m = __ballot(bad);
    if (threadIdx.x == 0) *flag = (m != 0ULL) ? 1 : 0;
}

__global__ void convert_kernel(const void* p, int* out, int n, const int* flag) {
    int i = blockIdx.x * blockDim.x + threadIdx.x;
    if (i < n) {
        if (*flag) out[i] = ((const int*)p)[i];
        else       out[i] = (int)((const long long*)p)[i];
    }
}

// ---------------------------------------------------------------------------
// Degree of incoming edges (self-loop handled separately; dinv uses deg+1)
// ---------------------------------------------------------------------------
__global__ void deg_init(int* deg, int n) {
    int i = blockIdx.x * blockDim.x + threadIdx.x;
    if (i < n) deg[i] = 0;
}

__global__ void deg_count(const int* __restrict__ dst, int* __restrict__ deg, int ne) {
    int i = blockIdx.x * blockDim.x + threadIdx.x;
    if (i < ne) atomicAdd(&deg[dst[i]], 1);
}

__global__ void dinv_kernel(const int* __restrict__ deg, float* __restrict__ dinv, int n) {
    int i = blockIdx.x * blockDim.x + threadIdx.x;
    if (i < n) dinv[i] = rsqrtf((float)(deg[i] + 1));
}

// ---------------------------------------------------------------------------
// Exclusive prefix sum over deg -> row_ptr (3 kernels, graph-capture safe)
// ---------------------------------------------------------------------------
__global__ void scan_block(const int* __restrict__ deg, int* __restrict__ incl,
                           int* __restrict__ partial, int n) {
    __shared__ int sh[256];
    int t = threadIdx.x;
    int i = blockIdx.x * 256 + t;
    sh[t] = (i < n) ? deg[i] : 0;
    __syncthreads();
    for (int off = 1; off < 256; off <<= 1) {
        int add = (t >= off) ? sh[t - off] : 0;
        __syncthreads();
        sh[t] += add;
        __syncthreads();
    }
    if (i < n) incl[i] = sh[t];
    if (t == 255) partial[blockIdx.x] = sh[255];
}

// single block of 512 threads; loops with carry if nb > 512
__global__ void scan_partials(int* partial, int nb) {
    __shared__ int sh[512];
    __shared__ int carry;
    int t = threadIdx.x;
    if (t == 0) carry = 0;
    __syncthreads();
    for (int base = 0; base < nb; base += 512) {
        int idx = base + t;
        sh[t] = (idx < nb) ? partial[idx] : 0;
        __syncthreads();
        for (int off = 1; off < 512; off <<= 1) {
            int add = (t >= off) ? sh[t - off] : 0;
            __syncthreads();
            sh[t] += add;
            __syncthreads();
        }
        int excl = carry + ((t == 0) ? 0 : sh[t - 1]);
        if (idx < nb) partial[idx] = excl;
        __syncthreads();
        if (t == 0) carry += sh[511];
        __syncthreads();
    }
}

__global__ void finalize_rowptr(const int* __restrict__ incl, const int* __restrict__ deg,
                                const int* __restrict__ partial,
                                int* __restrict__ row_ptr, int* __restrict__ cursor,
                                int n, int e_total) {
    int i = blockIdx.x * blockDim.x + threadIdx.x;
    if (i < n) {
        int v = partial[i >> 8] + incl[i] - deg[i];   // exclusive scan
        row_ptr[i] = v;
        cursor[i]  = v;
    }
    if (i == 0) row_ptr[n] = e_total;
}

// counting-sort scatter: csr_src holds sources grouped by destination
__global__ void scatter_edges(const int* __restrict__ src, const int* __restrict__ dst,
                              int* __restrict__ cursor, int* __restrict__ csr_src, int ne) {
    int i = blockIdx.x * blockDim.x + threadIdx.x;
    if (i < ne) {
        int pos = atomicAdd(&cursor[dst[i]], 1);
        csr_src[pos] = src[i];
    }
}

// ---------------------------------------------------------------------------
// hs[r][c] = dinv[r] * sum_k X[r][k] * W[k][c]. K = 128 fixed. NC in {128,64}.
// Block = 256 threads, each thread computes 16 contiguous cols of one row.
// ---------------------------------------------------------------------------
template <int NC, int RPB>
__launch_bounds__(256)
__global__ void gemm_scale(const float* __restrict__ X, const float* __restrict__ W,
                           const float* __restrict__ dinv,
                           float* __restrict__ hs, int nrows) {
    constexpr int K   = 128;
    constexpr int TPR = NC / 16;                 // threads per row
    constexpr int XLD = K + 4;                   // padded X stride
    __shared__ float Wl[K * NC];
    __shared__ float Xl[RPB * XLD];

    const int tid  = threadIdx.x;
    const int row0 = blockIdx.x * RPB;

    for (int i = tid; i < K * NC / 4; i += 256)
        ((float4*)Wl)[i] = ((const float4*)W)[i];

    for (int i = tid; i < RPB * K / 4; i += 256) {
        int r = i / (K / 4);
        int c = i % (K / 4);
        int gr = row0 + r;
        float4 v = (gr < nrows) ? ((const float4*)(X + (size_t)gr * K))[c]
                                : make_float4(0.f, 0.f, 0.f, 0.f);
        *((float4*)(Xl + r * XLD + c * 4)) = v;
    }
    __syncthreads();

    const int rl = tid / TPR;
    const int c0 = (tid % TPR) * 16;
    float a[16];
#pragma unroll
    for (int j = 0; j < 16; ++j) a[j] = 0.f;

    const float* xp = Xl + rl * XLD;
#pragma unroll 4
    for (int k = 0; k < K; ++k) {
        float xv = xp[k];
#pragma unroll
        for (int j = 0; j < 16; ++j)
            a[j] += xv * Wl[k * NC + c0 + j];
    }

    int gr = row0 + rl;
    if (gr < nrows) {
        float dv = dinv[gr];
        float* hp = hs + (size_t)gr * NC + c0;
#pragma unroll
        for (int j = 0; j < 16; ++j)
            hp[j] = a[j] * dv;
    }
}

// ---------------------------------------------------------------------------
// Fused aggregation + epilogue (no atomics):
//   out[node][c] = act( (hs[node][c] + sum_{e in CSR[node]} hs[src[e]][c])
//                       * dinv[node] + b[c] )
// F threads per node; F in {128, 64}; block = 256.
// ---------------------------------------------------------------------------
template <int F, bool RELU>
__launch_bounds__(256)
__global__ void aggregate_fused(const int* __restrict__ row_ptr,
                                const int* __restrict__ csr_src,
                                const float* __restrict__ hs,
                                const float* __restrict__ dinv,
                                const float* __restrict__ b,
                                float* __restrict__ out, int n) {
    constexpr int NPB = 256 / F;
    int node = blockIdx.x * NPB + threadIdx.x / F;
    int c    = threadIdx.x % F;
    if (node >= n) return;

    int beg = row_ptr[node];
    int end = row_ptr[node + 1];
    float acc = hs[(size_t)node * F + c];          // self-loop term

    // 2-stage software pipeline: overlap index fetch with data fetch
    if (beg < end) {
        int   s = csr_src[beg];
        float v = hs[(size_t)s * F + c];
        for (int e = beg + 1; e < end; ++e) {
            int   s2 = csr_src[e];
            float v2 = hs[(size_t)s2 * F + c];
            acc += v;
            v = v2;
        }
        acc += v;
    }

    float o = acc * dinv[node] + b[c];
    if (RELU) o = fmaxf(o, 0.f);
    out[(size_t)node * F + c] = o;
}

// ---------------------------------------------------------------------------
extern "C" void kernel_launch(void* const* d_in, const int* in_sizes, int n_in,
                              void* d_out, int out_size, void* d_ws, size_t ws_size,
                              hipStream_t stream) {
    const void*  edge = d_in[0];
    const float* x    = (const float*)d_in[1];
    const float* W1   = (const float*)d_in[2];
    const float* b1   = (const float*)d_in[3];
    const float* W2   = (const float*)d_in[4];
    const float* b2   = (const float*)d_in[5];
    float* out = (float*)d_out;

    const int E = in_sizes[0] / 2;          // edge_index is [2, E]
    const int N = in_sizes[1] / NFEATS;     // 100000

    // ---- workspace carve (256B-aligned regions) ----
    char* w = (char*)d_ws;
    auto carve = [&](size_t bytes) { void* p = w; w += (bytes + 255) & ~(size_t)255; return p; };
    int*   flag    = (int*)  carve(256);
    int*   src32   = (int*)  carve(sizeof(int) * (size_t)E);
    int*   dst32   = (int*)  carve(sizeof(int) * (size_t)E);
    int*   csr_src = (int*)  carve(sizeof(int) * (size_t)E);
    int*   deg     = (int*)  carve(sizeof(int) * (size_t)N);
    int*   incl    = (int*)  carve(sizeof(int) * (size_t)N);
    int*   partial = (int*)  carve(sizeof(int) * 4096);
    int*   row_ptr = (int*)  carve(sizeof(int) * ((size_t)N + 1));
    int*   cursor  = (int*)  carve(sizeof(int) * (size_t)N);
    float* dinv    = (float*)carve(sizeof(float) * (size_t)N);
    float* hs1     = (float*)carve(sizeof(float) * (size_t)N * NHIDS);
    float* h1      = (float*)carve(sizeof(float) * (size_t)N * NHIDS);
    float* hs2     = (float*)carve(sizeof(float) * (size_t)N * NOUT);

    const int B  = 256;
    const int nb = (N + 255) / 256;         // scan blocks (391 for N=100K)

    // edge-index normalization
    detect_kernel<<<1, 64, 0, stream>>>(edge, flag, (long long)N);
    convert_kernel<<<(2 * E + B - 1) / B, B, 0, stream>>>(edge, src32, 2 * E, flag);

    // degrees -> dinv
    deg_init<<<(N + B - 1) / B, B, 0, stream>>>(deg, N);
    deg_count<<<(E + B - 1) / B, B, 0, stream>>>(dst32, deg, E);
    dinv_kernel<<<(N + B - 1) / B, B, 0, stream>>>(deg, dinv, N);

    // CSR build: scan degrees -> row_ptr, then counting-sort scatter
    scan_block<<<nb, 256, 0, stream>>>(deg, incl, partial, N);
    scan_partials<<<1, 512, 0, stream>>>(partial, nb);
    finalize_rowptr<<<(N + B - 1) / B, B, 0, stream>>>(incl, deg, partial, row_ptr, cursor, N, E);
    scatter_edges<<<(E + B - 1) / B, B, 0, stream>>>(src32, dst32, cursor, csr_src, E);

    // ---- layer 1 ----  (NPB = 256/F nodes per block)
    gemm_scale<NHIDS, 32><<<(N + 31) / 32, B, 0, stream>>>(x, W1, dinv, hs1, N);
    {
        constexpr int NPB1 = 256 / NHIDS;   // = 2
        aggregate_fused<NHIDS, true><<<(N + NPB1 - 1) / NPB1, B, 0, stream>>>(
            row_ptr, csr_src, hs1, dinv, b1, h1, N);
    }

    // ---- layer 2 ----
    gemm_scale<NOUT, 64><<<(N + 63) / 64, B, 0, stream>>>(h1, W2, dinv, hs2, N);
    {
        constexpr int NPB2 = 256 / NOUT;    // = 4
        aggregate_fused<NOUT, false><<<(N + NPB2 - 1) / NPB2, B, 0, stream>>>(
            row_ptr, csr_src, hs2, dinv, b2, out, N);
    }
}

// Round 4
// 518.677 us; speedup vs baseline: 8.6385x; 1.5447x over previous
//
#include <hip/hip_runtime.h>
#include <cstdint>
#include <cstddef>

#define NFEATS 128
#define NHIDS  128
#define NOUT   64

using bf16x8 = __attribute__((ext_vector_type(8))) short;
using f32x4  = __attribute__((ext_vector_type(4))) float;

__device__ inline unsigned short f2bf(float f) {           // round-to-nearest-even
    union { float f; unsigned int u; } v; v.f = f;
    unsigned int r = (v.u + 0x7FFFu + ((v.u >> 16) & 1u)) >> 16;
    return (unsigned short)r;
}
__device__ inline float bflo(unsigned int u) { return __uint_as_float(u << 16); }
__device__ inline float bfhi(unsigned int u) { return __uint_as_float(u & 0xFFFF0000u); }

// ---------------------------------------------------------------------------
// Edge-index dtype detection (int64 vs int32). flag=1 -> int32.
// ---------------------------------------------------------------------------
__global__ void detect_kernel(const void* p, int* flag, long long n_nodes) {
    const long long* q = (const long long*)p;
    long long v = q[threadIdx.x];
    int bad = (v < 0 || v >= n_nodes) ? 1 : 0;
    unsigned long long m = __ballot(bad);
    if (threadIdx.x == 0) *flag = (m != 0ULL) ? 1 : 0;
}

__global__ void convert_kernel(const void* p, int* out, int n, const int* flag) {
    int i = blockIdx.x * blockDim.x + threadIdx.x;
    if (i < n) {
        if (*flag) out[i] = ((const int*)p)[i];
        else       out[i] = (int)((const long long*)p)[i];
    }
}

// ---------------------------------------------------------------------------
// Degrees -> dinv
// ---------------------------------------------------------------------------
__global__ void deg_init(int* deg, int n) {
    int i = blockIdx.x * blockDim.x + threadIdx.x;
    if (i < n) deg[i] = 0;
}

__global__ void deg_count(const int* __restrict__ dst, int* __restrict__ deg, int ne) {
    int i = blockIdx.x * blockDim.x + threadIdx.x;
    if (i < ne) atomicAdd(&deg[dst[i]], 1);
}

__global__ void dinv_kernel(const int* __restrict__ deg, float* __restrict__ dinv, int n) {
    int i = blockIdx.x * blockDim.x + threadIdx.x;
    if (i < n) dinv[i] = rsqrtf((float)(deg[i] + 1));
}

// ---------------------------------------------------------------------------
// Exclusive scan -> row_ptr ; counting-sort scatter -> csr_src
// ---------------------------------------------------------------------------
__global__ void scan_block(const int* __restrict__ deg, int* __restrict__ incl,
                           int* __restrict__ partial, int n) {
    __shared__ int sh[256];
    int t = threadIdx.x;
    int i = blockIdx.x * 256 + t;
    sh[t] = (i < n) ? deg[i] : 0;
    __syncthreads();
    for (int off = 1; off < 256; off <<= 1) {
        int add = (t >= off) ? sh[t - off] : 0;
        __syncthreads();
        sh[t] += add;
        __syncthreads();
    }
    if (i < n) incl[i] = sh[t];
    if (t == 255) partial[blockIdx.x] = sh[255];
}

__global__ void scan_partials(int* partial, int nb) {
    __shared__ int sh[512];
    __shared__ int carry;
    int t = threadIdx.x;
    if (t == 0) carry = 0;
    __syncthreads();
    for (int base = 0; base < nb; base += 512) {
        int idx = base + t;
        sh[t] = (idx < nb) ? partial[idx] : 0;
        __syncthreads();
        for (int off = 1; off < 512; off <<= 1) {
            int add = (t >= off) ? sh[t - off] : 0;
            __syncthreads();
            sh[t] += add;
            __syncthreads();
        }
        int excl = carry + ((t == 0) ? 0 : sh[t - 1]);
        if (idx < nb) partial[idx] = excl;
        __syncthreads();
        if (t == 0) carry += sh[511];
        __syncthreads();
    }
}

__global__ void finalize_rowptr(const int* __restrict__ incl, const int* __restrict__ deg,
                                const int* __restrict__ partial,
                                int* __restrict__ row_ptr, int* __restrict__ cursor,
                                int n, int e_total) {
    int i = blockIdx.x * blockDim.x + threadIdx.x;
    if (i < n) {
        int v = partial[i >> 8] + incl[i] - deg[i];
        row_ptr[i] = v;
        cursor[i]  = v;
    }
    if (i == 0) row_ptr[n] = e_total;
}

__global__ void scatter_edges(const int* __restrict__ src, const int* __restrict__ dst,
                              int* __restrict__ cursor, int* __restrict__ csr_src, int ne) {
    int i = blockIdx.x * blockDim.x + threadIdx.x;
    if (i < ne) {
        int pos = atomicAdd(&cursor[dst[i]], 1);
        csr_src[pos] = src[i];
    }
}

// ---------------------------------------------------------------------------
// fp32 -> bf16 bulk convert (n multiple of 4)
// ---------------------------------------------------------------------------
__global__ void f32_to_bf16(const float* __restrict__ in, unsigned short* __restrict__ out, int n4) {
    int i = blockIdx.x * blockDim.x + threadIdx.x;
    if (i < n4) {
        float4 v = ((const float4*)in)[i];
        ushort4 o;
        o.x = f2bf(v.x); o.y = f2bf(v.y); o.z = f2bf(v.z); o.w = f2bf(v.w);
        ((ushort4*)out)[i] = o;
    }
}

// W [K][NC] fp32 row-major  ->  Wt [NC][K] bf16 (transposed)
__global__ void wt_bf16(const float* __restrict__ W, unsigned short* __restrict__ Wt,
                        int K, int NC) {
    int i = blockIdx.x * blockDim.x + threadIdx.x;
    if (i < K * NC) {
        int k = i / NC, n = i % NC;
        Wt[n * K + k] = f2bf(W[i]);
    }
}

// ---------------------------------------------------------------------------
// MFMA GEMM: hs[r][c] = bf16( dinv[r] * sum_k Xb[r][k] * W[k][c] )
// Xb bf16 [nrows][128], Wt bf16 [NC][128] (pre-transposed). Block = 256 (4
// waves), M-tile = 64 rows (16/wave), full NC per block.
// Layouts (verified, learn_hip m89/m91/m120):
//   A: lane holds A[m=lane&15][k=(lane>>4)*8+j]
//   B: lane holds B[k=(lane>>4)*8+j][n=lane&15]  (Wl stored [n][k])
//   D: lane holds D[row=(lane>>4)*4+i][col=lane&15]
// KP=136 pads k-stride to 272 B -> 2-way LDS bank aliasing (free).
// ---------------------------------------------------------------------------
template <int NC>
__launch_bounds__(256)
__global__ void gemm_mfma(const unsigned short* __restrict__ Xb,
                          const unsigned short* __restrict__ Wt,
                          const float* __restrict__ dinv,
                          unsigned short* __restrict__ hs, int nrows) {
    constexpr int K  = 128;
    constexpr int KP = 136;
    __shared__ __align__(16) unsigned short Xl[64 * KP];
    __shared__ __align__(16) unsigned short Wl[NC * KP];

    const int tid  = threadIdx.x;
    const int row0 = blockIdx.x * 64;

    for (int i = tid; i < 64 * (K / 4); i += 256) {          // stage X tile
        int r  = i >> 5;                                      // K/4 == 32
        int c4 = i & 31;
        int gr = row0 + r;
        ushort4 v = make_ushort4(0, 0, 0, 0);
        if (gr < nrows) v = ((const ushort4*)(Xb + (size_t)gr * K))[c4];
        *(ushort4*)(Xl + r * KP + c4 * 4) = v;
    }
    for (int i = tid; i < NC * (K / 4); i += 256) {          // stage W^T
        int r  = i >> 5;
        int c4 = i & 31;
        ushort4 v = ((const ushort4*)(Wt + (size_t)r * K))[c4];
        *(ushort4*)(Wl + r * KP + c4 * 4) = v;
    }
    __syncthreads();

    const int wv   = tid >> 6;
    const int lane = tid & 63;
    const int m    = lane & 15;
    const int q    = lane >> 4;

    bf16x8 af[4];
#pragma unroll
    for (int kt = 0; kt < 4; ++kt)
        af[kt] = *(const bf16x8*)(Xl + (wv * 16 + m) * KP + kt * 32 + q * 8);

    const int rbase = row0 + wv * 16 + q * 4;
    float dv[4];
#pragma unroll
    for (int i = 0; i < 4; ++i)
        dv[i] = (rbase + i < nrows) ? dinv[rbase + i] : 0.f;

#pragma unroll
    for (int nt = 0; nt < NC / 16; ++nt) {
        f32x4 acc = {0.f, 0.f, 0.f, 0.f};
#pragma unroll
        for (int kt = 0; kt < 4; ++kt) {
            bf16x8 bfr = *(const bf16x8*)(Wl + (nt * 16 + m) * KP + kt * 32 + q * 8);
            acc = __builtin_amdgcn_mfma_f32_16x16x32_bf16(af[kt], bfr, acc, 0, 0, 0);
        }
#pragma unroll
        for (int i = 0; i < 4; ++i) {
            int g = rbase + i;
            if (g < nrows)
                hs[(size_t)g * NC + nt * 16 + m] = f2bf(acc[i] * dv[i]);
        }
    }
}

// ---------------------------------------------------------------------------
// CSR gather-reduce + epilogue, bf16 features (fp32 accumulate):
//   out[node][:] = act( (hs[node] + sum_{s in CSR[node]} hs[s]) * dinv + b )
// TPN = F/2 threads per node, one bf16x2 word per thread.
// ---------------------------------------------------------------------------
template <int F, bool RELU, bool OUTBF>
__launch_bounds__(256)
__global__ void aggregate_bf16(const int* __restrict__ row_ptr,
                               const int* __restrict__ csr_src,
                               const unsigned int* __restrict__ hsu,
                               const float* __restrict__ dinv,
                               const float* __restrict__ b,
                               void* __restrict__ out, int n) {
    constexpr int TPN = F / 2;
    constexpr int NPB = 256 / TPN;
    int node = blockIdx.x * NPB + threadIdx.x / TPN;
    int t    = threadIdx.x % TPN;
    if (node >= n) return;

    unsigned int u = hsu[(size_t)node * TPN + t];            // self-loop term
    float a0 = bflo(u), a1 = bfhi(u);

    int beg = row_ptr[node], end = row_ptr[node + 1];
    if (beg < end) {                                          // 2-stage pipeline
        int s = csr_src[beg];
        unsigned int v = hsu[(size_t)s * TPN + t];
        for (int e = beg + 1; e < end; ++e) {
            int s2 = csr_src[e];
            unsigned int v2 = hsu[(size_t)s2 * TPN + t];
            a0 += bflo(v); a1 += bfhi(v);
            v = v2;
        }
        a0 += bflo(v); a1 += bfhi(v);
    }

    float dvn = dinv[node];
    float o0 = a0 * dvn + b[2 * t];
    float o1 = a1 * dvn + b[2 * t + 1];
    if (RELU) { o0 = fmaxf(o0, 0.f); o1 = fmaxf(o1, 0.f); }
    if (OUTBF) {
        ((unsigned int*)out)[(size_t)node * TPN + t] =
            (unsigned int)f2bf(o0) | ((unsigned int)f2bf(o1) << 16);
    } else {
        ((float2*)out)[(size_t)node * TPN + t] = make_float2(o0, o1);
    }
}

// ---------------------------------------------------------------------------
extern "C" void kernel_launch(void* const* d_in, const int* in_sizes, int n_in,
                              void* d_out, int out_size, void* d_ws, size_t ws_size,
                              hipStream_t stream) {
    const void*  edge = d_in[0];
    const float* x    = (const float*)d_in[1];
    const float* W1   = (const float*)d_in[2];
    const float* b1   = (const float*)d_in[3];
    const float* W2   = (const float*)d_in[4];
    const float* b2   = (const float*)d_in[5];
    float* out = (float*)d_out;

    const int E = in_sizes[0] / 2;
    const int N = in_sizes[1] / NFEATS;

    char* w = (char*)d_ws;
    auto carve = [&](size_t bytes) { void* p = w; w += (bytes + 255) & ~(size_t)255; return p; };
    int*            flag    = (int*)           carve(256);
    int*            src32   = (int*)           carve(sizeof(int) * (size_t)E);
    int*            dst32   = (int*)           carve(sizeof(int) * (size_t)E);
    int*            csr_src = (int*)           carve(sizeof(int) * (size_t)E);
    int*            deg     = (int*)           carve(sizeof(int) * (size_t)N);
    int*            incl    = (int*)           carve(sizeof(int) * (size_t)N);
    int*            partial = (int*)           carve(sizeof(int) * 4096);
    int*            row_ptr = (int*)           carve(sizeof(int) * ((size_t)N + 1));
    int*            cursor  = (int*)           carve(sizeof(int) * (size_t)N);
    float*          dinv    = (float*)         carve(sizeof(float) * (size_t)N);
    unsigned short* xb      = (unsigned short*)carve(2 * (size_t)N * NFEATS);
    unsigned short* Wt1     = (unsigned short*)carve(2 * (size_t)NFEATS * NHIDS);
    unsigned short* Wt2     = (unsigned short*)carve(2 * (size_t)NHIDS * NOUT);
    unsigned short* hs1     = (unsigned short*)carve(2 * (size_t)N * NHIDS);
    unsigned short* h1      = (unsigned short*)carve(2 * (size_t)N * NHIDS);
    unsigned short* hs2     = (unsigned short*)carve(2 * (size_t)N * NOUT);

    const int B  = 256;
    const int nb = (N + 255) / 256;

    detect_kernel<<<1, 64, 0, stream>>>(edge, flag, (long long)N);
    convert_kernel<<<(2 * E + B - 1) / B, B, 0, stream>>>(edge, src32, 2 * E, flag);

    deg_init<<<(N + B - 1) / B, B, 0, stream>>>(deg, N);
    deg_count<<<(E + B - 1) / B, B, 0, stream>>>(dst32, deg, E);
    dinv_kernel<<<(N + B - 1) / B, B, 0, stream>>>(deg, dinv, N);

    scan_block<<<nb, 256, 0, stream>>>(deg, incl, partial, N);
    scan_partials<<<1, 512, 0, stream>>>(partial, nb);
    finalize_rowptr<<<(N + B - 1) / B, B, 0, stream>>>(incl, deg, partial, row_ptr, cursor, N, E);
    scatter_edges<<<(E + B - 1) / B, B, 0, stream>>>(src32, dst32, cursor, csr_src, E);

    // bf16 conversions
    {
        int n4 = N * NFEATS / 4;
        f32_to_bf16<<<(n4 + B - 1) / B, B, 0, stream>>>(x, xb, n4);
        wt_bf16<<<(NFEATS * NHIDS + B - 1) / B, B, 0, stream>>>(W1, Wt1, NFEATS, NHIDS);
        wt_bf16<<<(NHIDS * NOUT + B - 1) / B, B, 0, stream>>>(W2, Wt2, NHIDS, NOUT);
    }

    // ---- layer 1 ----
    gemm_mfma<NHIDS><<<(N + 63) / 64, B, 0, stream>>>(xb, Wt1, dinv, hs1, N);
    aggregate_bf16<NHIDS, true, true><<<(N + 3) / 4, B, 0, stream>>>(
        row_ptr, csr_src, (const unsigned int*)hs1, dinv, b1, h1, N);

    // ---- layer 2 ----
    gemm_mfma<NOUT><<<(N + 63) / 64, B, 0, stream>>>(h1, Wt2, dinv, hs2, N);
    aggregate_bf16<NOUT, false, false><<<(N + 7) / 8, B, 0, stream>>>(
        row_ptr, csr_src, (const unsigned int*)hs2, dinv, b2, out, N);
}